// Round 6
// baseline (395.970 us; speedup 1.0000x reference)
//
#include <hip/hip_runtime.h>
#include <cstdint>
#include <cstddef>

#define DIMN 2048
#define SEQ  2048
#define NB   2
#define NH   16
#define DH   128
#define NQT  (SEQ / 128)    // 16 q-tiles
#define NBH  (NB * NH)      // 32

typedef __bf16 bf16x8 __attribute__((ext_vector_type(8)));
typedef float  f32x4  __attribute__((ext_vector_type(4)));
typedef bf16x8 __attribute__((may_alias)) bf16x8_a;
typedef ushort4 __attribute__((may_alias)) ushort4_a;
typedef float4 __attribute__((may_alias)) float4_a;

// ---- bf16 <-> f32 helpers on raw ushort storage (RNE, matches np/jnp) ----
__device__ __forceinline__ float b2f(unsigned short b) {
    unsigned u = ((unsigned)b) << 16; float f; __builtin_memcpy(&f, &u, 4); return f;
}
__device__ __forceinline__ unsigned short f2b(float f) {
    unsigned u; __builtin_memcpy(&u, &f, 4);
    u = (u + 0x7FFFu + ((u >> 16) & 1u)) >> 16;
    return (unsigned short)u;
}
__device__ __forceinline__ __bf16 f2bf(float f) {
    unsigned short us = f2b(f); __bf16 h; __builtin_memcpy(&h, &us, 2); return h;
}

// dtype flag: freqs_cos[0]==1.0 -> fp32 word0 = 0x3F800000 (bf16 would be 0x3F803F80)
__device__ __forceinline__ bool dt_is_f32(const void* fc) {
    return ((const unsigned int*)fc)[0] == 0x3F800000u;
}

// async global->LDS, 16B per lane (LDS dest = wave-uniform base + lane*16)
__device__ __forceinline__ void gload_lds16(const unsigned short* g, unsigned short* l) {
    __builtin_amdgcn_global_load_lds(
        (const __attribute__((address_space(1))) void*)g,
        (__attribute__((address_space(3))) void*)l,
        16, 0, 0);
}

// ============== convert fp32 (or bf16 passthrough) -> bf16, 8 elems/thread ==============
__device__ __forceinline__ void conv8(const void* in, unsigned short* out, size_t i, bool isf32) {
    if (isf32) {
        const float* p = (const float*)in + i * 8;
        float4 lo = *(const float4_a*)p;
        float4 hi = *(const float4_a*)(p + 4);
        ushort4 a, b;
        a.x = f2b(lo.x); a.y = f2b(lo.y); a.z = f2b(lo.z); a.w = f2b(lo.w);
        b.x = f2b(hi.x); b.y = f2b(hi.y); b.z = f2b(hi.z); b.w = f2b(hi.w);
        *(ushort4_a*)(out + i * 8)     = a;
        *(ushort4_a*)(out + i * 8 + 4) = b;
    } else {
        const ushort4* p = (const ushort4*)((const char*)in + i * 16);
        *(ushort4_a*)(out + i * 8)     = p[0];
        *(ushort4_a*)(out + i * 8 + 4) = p[1];
    }
}

__global__ void convert_kernel(const void* __restrict__ in, unsigned short* __restrict__ out,
                               int n8, const void* __restrict__ dt)
{
    const bool isf32 = dt_is_f32(dt);
    int i = blockIdx.x * 256 + threadIdx.x;
    if (i >= n8) return;
    conv8(in, out, (size_t)i, isf32);
}

// fused convert of x, Wq, Wk, Wv in one launch (fused path only)
#define NX8 1048576   // NB*SEQ*DIMN/8
#define NW8 524288    // DIMN*DIMN/8
__global__ void convert4_kernel(const void* __restrict__ x,  const void* __restrict__ wq,
                                const void* __restrict__ wk, const void* __restrict__ wv,
                                unsigned short* __restrict__ xb,
                                unsigned short* __restrict__ wqkv,
                                const void* __restrict__ dt)
{
    const bool isf32 = dt_is_f32(dt);
    int i = blockIdx.x * 256 + threadIdx.x;
    if (i < NX8) { conv8(x, xb, (size_t)i, isf32); return; }
    int j = i - NX8;
    int w = j / NW8, o = j - w * NW8;
    const void* src = (w == 0) ? wq : (w == 1) ? wk : wv;
    conv8(src, wqkv + (size_t)w * DIMN * DIMN, (size_t)o, isf32);
}

// =====================================================================
// "bt" GEMM (m97 128x128 structure), kept for non-fused path.
// =====================================================================
__global__ __launch_bounds__(256, 2) void gemm_bt(
    const unsigned short* __restrict__ A, const unsigned short* __restrict__ B,
    void* __restrict__ C, const void* __restrict__ dt, int cmode,
    int K, int lda, int ldb, int ldc, int Hz,
    long long sAb, long long sAh, long long sBb, long long sBh,
    long long sCb, long long sCh, float scale)
{
    const bool cf32 = cmode && dt_is_f32(dt);

    const int gx = gridDim.x, gy = gridDim.y;
    const int nwg = gx * gy * gridDim.z;
    const int fid = (blockIdx.z * gy + blockIdx.y) * gx + blockIdx.x;
    const int qq = nwg >> 3, rr = nwg & 7, xc = fid & 7, rem = fid >> 3;
    const int sid = (xc < rr ? xc * (qq + 1) : rr * (qq + 1) + (xc - rr) * qq) + rem;
    const int bx = sid % gx;
    const int t_ = sid / gx;
    const int by = t_ % gy;
    const int z  = t_ / gy;

    int zb = z / Hz, zh = z - zb * Hz;
    const unsigned short* Az = A + zb * sAb + zh * sAh;
    const unsigned short* Bz = B + zb * sBb + zh * sBh;
    const long long coffz = zb * sCb + zh * sCh;
    const int m0 = by * 128, n0 = bx * 128;

    __shared__ alignas(16) unsigned short sA[128 * 32];
    __shared__ alignas(16) unsigned short sB[128 * 32];

    const int tid  = threadIdx.x;
    const int lane = tid & 63, wave = tid >> 6;
    const int waveM = wave >> 1, waveN = wave & 1;

    const int rowA = tid >> 2;          // 0..63
    const int c8   = (tid & 3) << 3;    // 0,8,16,24
    const unsigned short* gA0 = Az + (size_t)(m0 + rowA)      * lda + c8;
    const unsigned short* gA1 = Az + (size_t)(m0 + rowA + 64) * lda + c8;
    const unsigned short* gB0 = Bz + (size_t)(n0 + rowA)      * ldb + c8;
    const unsigned short* gB1 = Bz + (size_t)(n0 + rowA + 64) * ldb + c8;
    unsigned short* lA0 = sA + tid * 8;
    unsigned short* lA1 = sA + 2048 + tid * 8;
    unsigned short* lB0 = sB + tid * 8;
    unsigned short* lB1 = sB + 2048 + tid * 8;

    f32x4 acc[4][4];
    #pragma unroll
    for (int i = 0; i < 4; i++)
        #pragma unroll
        for (int j = 0; j < 4; j++)
            acc[i][j] = (f32x4){0.f, 0.f, 0.f, 0.f};

    const int fr = lane & 15, fq = lane >> 4;
    const int aoff = (waveM * 64 + fr) * 32 + fq * 8;
    const int boff = (waveN * 64 + fr) * 32 + fq * 8;

    for (int kt = 0; kt < K; kt += 32) {
        gload_lds16(gA0, lA0);
        gload_lds16(gA1, lA1);
        gload_lds16(gB0, lB0);
        gload_lds16(gB1, lB1);
        gA0 += 32; gA1 += 32; gB0 += 32; gB1 += 32;
        __syncthreads();

        bf16x8 af[4], bfr[4];
        #pragma unroll
        for (int mt = 0; mt < 4; mt++)
            af[mt] = *(const bf16x8_a*)(sA + aoff + mt * 16 * 32);
        #pragma unroll
        for (int nt = 0; nt < 4; nt++)
            bfr[nt] = *(const bf16x8_a*)(sB + boff + nt * 16 * 32);
        #pragma unroll
        for (int mt = 0; mt < 4; mt++)
            #pragma unroll
            for (int nt = 0; nt < 4; nt++)
                acc[mt][nt] = __builtin_amdgcn_mfma_f32_16x16x32_bf16(
                    af[mt], bfr[nt], acc[mt][nt], 0, 0, 0);
        __syncthreads();
    }

    const int crow0 = m0 + waveM * 64 + fq * 4;
    const int ccol0 = n0 + waveN * 64 + fr;
    #pragma unroll
    for (int mt = 0; mt < 4; mt++)
        #pragma unroll
        for (int nt = 0; nt < 4; nt++) {
            size_t base = (size_t)(crow0 + mt * 16) * ldc + (ccol0 + nt * 16);
            if (cf32) {
                float* Cz = (float*)C + coffz;
                #pragma unroll
                for (int r = 0; r < 4; r++)
                    Cz[base + (size_t)r * ldc] = acc[mt][nt][r] * scale;
            } else {
                unsigned short* Cz = (unsigned short*)C + coffz;
                #pragma unroll
                for (int r = 0; r < 4; r++)
                    Cz[base + (size_t)r * ldc] = f2b(acc[mt][nt][r] * scale);
            }
        }
}

// ============== RoPE in place on q_lin and k_lin (non-fused path only) ==============
// Q is PRE-SCALED by log2e/sqrt(DH) (flash uses exp2-domain softmax).
__global__ void rope_kernel(unsigned short* q, unsigned short* k,
                            const void* __restrict__ fc,
                            const void* __restrict__ fs)
{
    const bool isf32 = dt_is_f32(fc);
    int idx = blockIdx.x * 256 + threadIdx.x;   // 8-elem group
    unsigned short* p = blockIdx.y ? k : q;
    const float sc = blockIdx.y ? 1.0f : (0.08838834764831845f * 1.4426950408889634f);
    int row = idx >> 8;                         // [0, NB*SEQ)
    int e   = (idx & 255) << 3;                 // feature 0..2047 step 8
    int s   = row & (SEQ - 1);
    int j0  = (e & (DH - 1)) >> 1;              // 4 pairs j0..j0+3
    float c[4], sn[4];
    #pragma unroll
    for (int t = 0; t < 4; t++) {
        if (isf32) {
            c[t]  = ((const float*)fc)[s * 64 + j0 + t] * sc;
            sn[t] = ((const float*)fs)[s * 64 + j0 + t] * sc;
        } else {
            c[t]  = b2f(((const unsigned short*)fc)[s * 64 + j0 + t]) * sc;
            sn[t] = b2f(((const unsigned short*)fs)[s * 64 + j0 + t]) * sc;
        }
    }
    size_t off = (size_t)row * DIMN + e;
    ushort4 a = *(ushort4_a*)(p + off);
    ushort4 b = *(ushort4_a*)(p + off + 4);
    float xs[8] = {b2f(a.x), b2f(a.y), b2f(a.z), b2f(a.w),
                   b2f(b.x), b2f(b.y), b2f(b.z), b2f(b.w)};
    ushort4 oa, ob;
    oa.x = f2b(xs[0] * c[0] - xs[1] * sn[0]);
    oa.y = f2b(xs[0] * sn[0] + xs[1] * c[0]);
    oa.z = f2b(xs[2] * c[1] - xs[3] * sn[1]);
    oa.w = f2b(xs[2] * sn[1] + xs[3] * c[1]);
    ob.x = f2b(xs[4] * c[2] - xs[5] * sn[2]);
    ob.y = f2b(xs[4] * sn[2] + xs[5] * c[2]);
    ob.z = f2b(xs[6] * c[3] - xs[7] * sn[3]);
    ob.w = f2b(xs[6] * sn[3] + xs[7] * c[3]);
    *(ushort4_a*)(p + off)     = oa;
    *(ushort4_a*)(p + off + 4) = ob;
}

// ============== per-batch 2048x2048 transpose (non-fused path only) ==============
__global__ void transpose_kernel(const unsigned short* __restrict__ in,
                                 unsigned short* __restrict__ out)
{
    __shared__ unsigned short tile[32][33];
    int b = blockIdx.z;
    const unsigned short* ib = in + (size_t)b * SEQ * DIMN;
    unsigned short*       ob = out + (size_t)b * SEQ * DIMN;
    int t0 = blockIdx.x << 5, i0 = blockIdx.y << 5;
    int c = threadIdx.x & 31, r0 = threadIdx.x >> 5;
    for (int r = r0; r < 32; r += 8)
        tile[r][c] = ib[(size_t)(t0 + r) * DIMN + i0 + c];
    __syncthreads();
    for (int r = r0; r < 32; r += 8)
        ob[(size_t)(i0 + r) * SEQ + t0 + c] = tile[c][r];
}

// =====================================================================
// Fused flash attention (causal). Swapped QK^T; exp2-domain softmax.
// LDS 48 KB -> 3 blocks/CU (was 80 KB / 2 blocks; both pipes idle at
// 8 waves/CU = latency-bound): K double-buffered (async DMA, hidden),
// V single-buffered (staged at iter end, consumed after next QK+softmax),
// P OVERLAID into the dead sK[cur] buffer after QK^T (barrier between
// last kf read and first P write).
// =====================================================================
__global__ __launch_bounds__(256, 2) void flash_kernel(
    const unsigned short* __restrict__ q_lin,
    const unsigned short* __restrict__ k_lin,
    const unsigned short* __restrict__ vTg,
    unsigned short* __restrict__ ctxT)
{
    __shared__ alignas(16) unsigned short sK[2][64 * 128];   // 32 KB; sK[cur] doubles as P
    __shared__ alignas(16) unsigned short sV[128 * 64];      // 16 KB, single buffer

    const int idx  = blockIdx.x;                 // [0, NQT*NBH)
    const int slot = idx >> 5;
    const int qt   = (slot < 8) ? (15 - slot) : (slot - 8);  // pair-balanced
    const int z    = idx & (NBH - 1);
    const int b    = z >> 4, h = z & 15;

    const unsigned short* Qg = q_lin + ((size_t)(b * SEQ + qt * 128)) * DIMN + h * DH;
    const unsigned short* Kg = k_lin + (size_t)b * SEQ * DIMN + h * DH;
    const unsigned short* Vg = vTg  + (size_t)b * SEQ * DIMN + (size_t)h * DH * SEQ;
    unsigned short*       Cg = ctxT + (size_t)b * SEQ * DIMN + (size_t)h * DH * SEQ;

    const int tid  = threadIdx.x;
    const int lane = tid & 63, wave = tid >> 6;
    const int fr = lane & 15, fq = lane >> 4;

    // Q fragments (B-operand): row = wave*32 + qq*16 + fr, k = kt*32 + fq*8 + j
    bf16x8 qf[2][4];
    #pragma unroll
    for (int mt = 0; mt < 2; mt++)
        #pragma unroll
        for (int kt = 0; kt < 4; kt++)
            qf[mt][kt] = *(const bf16x8_a*)(Qg + (size_t)(wave * 32 + mt * 16 + fr) * DIMN + kt * 32 + fq * 8);

    f32x4 o_acc[2][8];
    #pragma unroll
    for (int mt = 0; mt < 2; mt++)
        #pragma unroll
        for (int nt = 0; nt < 8; nt++)
            o_acc[mt][nt] = (f32x4){0.f, 0.f, 0.f, 0.f};
    // column-wise stats: lane holds m,l for q = wave*32 + qq*16 + fr (log2 domain m)
    float m_st[2], l_st[2];
    m_st[0] = m_st[1] = -1e30f;
    l_st[0] = l_st[1] = 0.f;

#define FSTAGE_K(pb, jn) do { \
    const unsigned short* Kt_ = Kg + (size_t)(jn) * 64 * DIMN; \
    _Pragma("unroll") \
    for (int i_ = 0; i_ < 4; i_++) { \
        int cc_ = tid + i_ * 256; int r_ = cc_ >> 4, c_ = cc_ & 15; \
        gload_lds16(Kt_ + (size_t)r_ * DIMN + ((c_ ^ (r_ & 7)) << 3), &sK[pb][cc_ * 8]); \
    } \
} while (0)
#define FSTAGE_V(jn) do { \
    const unsigned short* Vt_ = Vg + (jn) * 64; \
    _Pragma("unroll") \
    for (int i_ = 0; i_ < 4; i_++) { \
        int cc_ = tid + i_ * 256; int r_ = cc_ >> 3, c_ = cc_ & 7; \
        gload_lds16(Vt_ + (size_t)r_ * SEQ + ((c_ ^ (r_ & 7)) << 3), &sV[cc_ * 8]); \
    } \
} while (0)

    const int jmax = 2 * qt + 2;

    FSTAGE_K(0, 0);
    FSTAGE_V(0);

    for (int jt = 0; jt < jmax; jt++) {
        const int cur = jt & 1;
        if (jt + 1 < jmax) {
            FSTAGE_K(cur ^ 1, jt + 1);           // async into other K buffer
            asm volatile("s_waitcnt vmcnt(4)");  // K(jt)+V(jt) landed; K(jt+1) in flight
        } else {
            asm volatile("s_waitcnt vmcnt(0)");
        }
        __builtin_amdgcn_s_barrier();

        // S^T = K . Q^T : lane holds col q = qq*16+fr, rows t = tt*16+fq*4+r
        f32x4 sT[4][2];
        #pragma unroll
        for (int tt = 0; tt < 4; tt++)
            #pragma unroll
            for (int qq = 0; qq < 2; qq++)
                sT[tt][qq] = (f32x4){0.f, 0.f, 0.f, 0.f};
        __builtin_amdgcn_s_setprio(1);
        #pragma unroll
        for (int kt = 0; kt < 4; kt++) {
            bf16x8 kf[4];
            #pragma unroll
            for (int tt = 0; tt < 4; tt++) {
                const int row = tt * 16 + fr;
                kf[tt] = *(const bf16x8_a*)&sK[cur][row * 128 + (((kt * 4 + fq) ^ (fr & 7)) << 3)];
            }
            #pragma unroll
            for (int tt = 0; tt < 4; tt++)
                #pragma unroll
                for (int qq = 0; qq < 2; qq++)
                    sT[tt][qq] = __builtin_amdgcn_mfma_f32_16x16x32_bf16(
                        kf[tt], qf[qq][kt], sT[tt][qq], 0, 0, 0);
        }
        __builtin_amdgcn_s_setprio(0);

        if (jt >= 2 * qt) {
            #pragma unroll
            for (int tt = 0; tt < 4; tt++)
                #pragma unroll
                for (int qq = 0; qq < 2; qq++)
                    #pragma unroll
                    for (int r = 0; r < 4; r++) {
                        int trel = jt * 64 + tt * 16 + fq * 4 + r - qt * 128;
                        int qrow = wave * 32 + qq * 16 + fr;
                        if (trel > qrow) sT[tt][qq][r] = -1e30f;
                    }
        }

        // per-q max: 15 in-lane fmax + 2 shfls
        float pm[2];
        #pragma unroll
        for (int qq = 0; qq < 2; qq++) {
            float rm = sT[0][qq][0];
            #pragma unroll
            for (int tt = 0; tt < 4; tt++)
                #pragma unroll
                for (int r = 0; r < 4; r++)
                    if (tt || r) rm = fmaxf(rm, sT[tt][qq][r]);
            rm = fmaxf(rm, __shfl_xor(rm, 16, 64));
            rm = fmaxf(rm, __shfl_xor(rm, 32, 64));
            pm[qq] = rm;
        }

        // all waves done reading sK[cur] -> it becomes the P buffer
        __builtin_amdgcn_s_barrier();
        unsigned short* sPp = &sK[cur][0];

        bool need = (pm[0] > m_st[0] + 8.0f) || (pm[1] > m_st[1] + 8.0f);
        if (__any((int)need)) {
            float alc[2];
            #pragma unroll
            for (int qq = 0; qq < 2; qq++) {
                float mn = fmaxf(m_st[qq], pm[qq]);
                alc[qq] = __builtin_amdgcn_exp2f(m_st[qq] - mn);
                m_st[qq] = mn;
                l_st[qq] *= alc[qq];
            }
            #pragma unroll
            for (int mt = 0; mt < 2; mt++) {
                float a[4];
                #pragma unroll
                for (int r = 0; r < 4; r++)
                    a[r] = __shfl(alc[mt], fq * 4 + r, 64);
                #pragma unroll
                for (int nt = 0; nt < 8; nt++)
                    #pragma unroll
                    for (int r = 0; r < 4; r++)
                        o_acc[mt][nt][r] *= a[r];
            }
        }

        // P = exp2(S^T - m) -> packed b64 stores into overlay
        float ps[2] = {0.f, 0.f};
        #pragma unroll
        for (int qq = 0; qq < 2; qq++) {
            const int qrow = wave * 32 + qq * 16 + fr;
            #pragma unroll
            for (int tt = 0; tt < 4; tt++) {
                float p0 = __builtin_amdgcn_exp2f(sT[tt][qq][0] - m_st[qq]);
                float p1 = __builtin_amdgcn_exp2f(sT[tt][qq][1] - m_st[qq]);
                float p2 = __builtin_amdgcn_exp2f(sT[tt][qq][2] - m_st[qq]);
                float p3 = __builtin_amdgcn_exp2f(sT[tt][qq][3] - m_st[qq]);
                ps[qq] += (p0 + p1) + (p2 + p3);
                ushort4 w;
                w.x = f2b(p0); w.y = f2b(p1); w.z = f2b(p2); w.w = f2b(p3);
                const int cpos = (tt * 2 + (fq >> 1)) ^ (qrow & 7);
                *(ushort4_a*)(sPp + qrow * 64 + cpos * 8 + (fq & 1) * 4) = w;
            }
        }
        #pragma unroll
        for (int qq = 0; qq < 2; qq++) {
            float s = ps[qq];
            s += __shfl_xor(s, 16, 64);
            s += __shfl_xor(s, 32, 64);
            l_st[qq] += s;
        }

        // O += P . V
        __builtin_amdgcn_s_setprio(1);
        #pragma unroll
        for (int kt = 0; kt < 2; kt++) {
            bf16x8 pf[2], vf[8];
            #pragma unroll
            for (int mt = 0; mt < 2; mt++) {
                int prow = wave * 32 + mt * 16 + fr;
                int cw   = (kt * 4 + fq) ^ (prow & 7);
                pf[mt] = *(const bf16x8_a*)(sPp + prow * 64 + (cw << 3));
            }
            #pragma unroll
            for (int nt = 0; nt < 8; nt++) {
                const int row = nt * 16 + fr;
                vf[nt] = *(const bf16x8_a*)&sV[row * 64 + (((kt * 4 + fq) ^ (fr & 7)) << 3)];
            }
            #pragma unroll
            for (int mt = 0; mt < 2; mt++)
                #pragma unroll
                for (int nt = 0; nt < 8; nt++)
                    o_acc[mt][nt] = __builtin_amdgcn_mfma_f32_16x16x32_bf16(
                        pf[mt], vf[nt], o_acc[mt][nt], 0, 0, 0);
        }
        __builtin_amdgcn_s_setprio(0);
        __builtin_amdgcn_s_barrier();                // all waves done reading sV & P
        if (jt + 1 < jmax) FSTAGE_V(jt + 1);         // overwrite sV now
    }

    // epilogue: O /= l (broadcast col-wise l to row layout), write ctxT[dh][s]
    #pragma unroll
    for (int mt = 0; mt < 2; mt++) {
        float invc = 1.0f / l_st[mt];
        float inv[4];
        #pragma unroll
        for (int r = 0; r < 4; r++)
            inv[r] = __shfl(invc, fq * 4 + r, 64);
        const int s0 = qt * 128 + wave * 32 + mt * 16 + fq * 4;
        #pragma unroll
        for (int nt = 0; nt < 8; nt++) {
            ushort4 w;
            w.x = f2b(o_acc[mt][nt][0] * inv[0]);
            w.y = f2b(o_acc[mt][nt][1] * inv[1]);
            w.z = f2b(o_acc[mt][nt][2] * inv[2]);
            w.w = f2b(o_acc[mt][nt][3] * inv[3]);
            int dh = nt * 16 + fr;
            *(ushort4_a*)(Cg + (size_t)dh * SEQ + s0) = w;
        }
    }
}

// =====================================================================
// 256x256 8-phase Q/K GEMM (T1..T5) with FUSED RoPE epilogue.
// z=0 -> Q (pre-scaled by log2e/sqrt(DH)), z=1 -> K. RoPE pair partner
// via __shfl_xor(acc,1) (col parity == fr parity); cos/sin read from
// the ORIGINAL fc/fs inputs (f32 or bf16). Replaces the rope kernel and
// removes one bf16 rounding of Q/K.
// =====================================================================
#define NIT16 16   // K=2048 / 128 per iteration (2 K-tiles of 64)

__global__ __launch_bounds__(512, 2) void gemm256_qkv(
    const unsigned short* __restrict__ A,
    const unsigned short* __restrict__ Bw,
    unsigned short* __restrict__ Cqk,
    const void* __restrict__ fc,
    const void* __restrict__ fs)
{
    __shared__ alignas(16) unsigned short sA[2][16384];   // [dbuf][256 rows][64 cols]
    __shared__ alignas(16) unsigned short sB[2][16384];

    const int fid = (blockIdx.z * 16 + blockIdx.y) * 8 + blockIdx.x;
    const int sid = (fid & 7) * 32 + (fid >> 3);
    const int bx = sid & 7, by = (sid >> 3) & 15, z = sid >> 7;

    const unsigned short* Bz = Bw + (size_t)z * DIMN * DIMN;
    const int n0 = bx << 8, m0 = by << 8;

    const int tid  = threadIdx.x;
    const int lane = tid & 63, wave = tid >> 6;
    const int wm = wave >> 2, wn = wave & 3;
    const int fr = lane & 15, fq = lane >> 4;

    const int srow = tid >> 3, sslot = tid & 7;
    const unsigned short* gA_base = A  + (size_t)(m0 + srow) * DIMN + ((sslot ^ (srow & 7)) << 3);
    const unsigned short* gB_base = Bz + (size_t)(n0 + srow) * DIMN + ((sslot ^ (srow & 7)) << 3);

    const int arow = wm * 128 + fr;
    const int brow = wn * 64 + fr;

    f32x4 acc[8][4];
    #pragma unroll
    for (int i = 0; i < 8; i++)
        #pragma unroll
        for (int j = 0; j < 4; j++)
            acc[i][j] = (f32x4){0.f, 0.f, 0.f, 0.f};

#define STAGE_A(h, t, pb) do { \
    const unsigned short* g_ = gA_base + (size_t)((h) * 128) * DIMN + (size_t)(t) * 64; \
    unsigned short* l_ = &sA[pb][(h) * 8192] + tid * 8; \
    gload_lds16(g_, l_); \
    gload_lds16(g_ + (size_t)(64 * DIMN), l_ + 4096); \
} while (0)
#define STAGE_B(h, t, pb) do { \
    const unsigned short* g_ = gB_base + (size_t)((h) * 128) * DIMN + (size_t)(t) * 64; \
    unsigned short* l_ = &sB[pb][(h) * 8192] + tid * 8; \
    gload_lds16(g_, l_); \
    gload_lds16(g_ + (size_t)(64 * DIMN), l_ + 4096); \
} while (0)

#define LOAD_AF(dst, pb, rofs) do { \
    _Pragma("unroll") \
    for (int mi_ = 0; mi_ < 4; mi_++) { \
        const int ra_ = arow + (rofs) + mi_ * 16; \
        _Pragma("unroll") \
        for (int kc_ = 0; kc_ < 2; kc_++) \
            dst[mi_][kc_] = *(const bf16x8_a*)&sA[pb][(ra_ << 6) + (((kc_ * 4 + fq) ^ (ra_ & 7)) << 3)]; \
    } \
} while (0)
#define LOAD_BF(dst, pb, rofs) do { \
    _Pragma("unroll") \
    for (int ni_ = 0; ni_ < 2; ni_++) { \
        const int rb_ = brow + (rofs) + ni_ * 16; \
        _Pragma("unroll") \
        for (int kc_ = 0; kc_ < 2; kc_++) \
            dst[ni_][kc_] = *(const bf16x8_a*)&sB[pb][(rb_ << 6) + (((kc_ * 4 + fq) ^ (rb_ & 7)) << 3)]; \
    } \
} while (0)

#define MFMA4x2(AF, BF, MB, NBASE) do { \
    _Pragma("unroll") \
    for (int mi_ = 0; mi_ < 4; mi_++) \
    _Pragma("unroll") \
    for (int ni_ = 0; ni_ < 2; ni_++) \
    _Pragma("unroll") \
    for (int kc_ = 0; kc_ < 2; kc_++) \
        acc[(MB) + mi_][(NBASE) + ni_] = __builtin_amdgcn_mfma_f32_16x16x32_bf16( \
            AF[mi_][kc_], BF[ni_][kc_], acc[(MB) + mi_][(NBASE) + ni_], 0, 0, 0); \
} while (0)

#define GATE4 asm volatile("s_waitcnt vmcnt(4)")
#define GATE0 asm volatile("s_waitcnt vmcnt(0)")
#define NOPS  ((void)0)

#define KTILE(PB, SA0, SA1, SB0, SB1, GATE) do { \
    LOAD_AF(af0, PB, 0); \
    LOAD_BF(bf0, PB, 0); \
    SA0; \
    asm volatile("s_waitcnt lgkmcnt(8)"); \
    __builtin_amdgcn_s_barrier(); \
    asm volatile("s_waitcnt lgkmcnt(0)"); \
    __builtin_amdgcn_s_setprio(1); \
    MFMA4x2(af0, bf0, 0, 0); \
    __builtin_amdgcn_s_setprio(0); \
    __builtin_amdgcn_s_barrier(); \
    LOAD_BF(bf1, PB, 32); \
    SA1; \
    __builtin_amdgcn_s_barrier(); \
    asm volatile("s_waitcnt lgkmcnt(0)"); \
    __builtin_amdgcn_s_setprio(1); \
    MFMA4x2(af0, bf1, 0, 2); \
    __builtin_amdgcn_s_setprio(0); \
    __builtin_amdgcn_s_barrier(); \
    LOAD_AF(af1, PB, 64); \
    SB0; \
    __builtin_amdgcn_s_barrier(); \
    asm volatile("s_waitcnt lgkmcnt(0)"); \
    __builtin_amdgcn_s_setprio(1); \
    MFMA4x2(af1, bf1, 4, 2); \
    __builtin_amdgcn_s_setprio(0); \
    __builtin_amdgcn_s_barrier(); \
    SB1; \
    __builtin_amdgcn_s_barrier(); \
    __builtin_amdgcn_s_setprio(1); \
    MFMA4x2(af1, bf0, 4, 0); \
    __builtin_amdgcn_s_setprio(0); \
    GATE; \
    __builtin_amdgcn_s_barrier(); \
} while (0)

    STAGE_A(0, 0, 0); STAGE_A(1, 0, 0);
    STAGE_B(0, 0, 0); STAGE_B(1, 0, 0);
    STAGE_B(0, 1, 1); STAGE_B(1, 1, 1);
    asm volatile("s_waitcnt vmcnt(4)");
    __builtin_amdgcn_s_barrier();

    bf16x8 af0[4][2], af1[4][2], bf0[2][2], bf1[2][2];

    for (int it = 0; it < NIT16 - 1; ++it) {
        const int t1 = 2 * it + 1;
        KTILE(0, STAGE_A(0, t1, 1),     STAGE_A(1, t1, 1),
                 STAGE_B(0, t1 + 1, 0), STAGE_B(1, t1 + 1, 0), GATE4);
        KTILE(1, STAGE_A(0, t1 + 1, 0), STAGE_A(1, t1 + 1, 0),
                 STAGE_B(0, t1 + 2, 1), STAGE_B(1, t1 + 2, 1), GATE4);
    }
    KTILE(0, STAGE_A(0, 31, 1), STAGE_A(1, 31, 1), NOPS, NOPS, GATE0);
    KTILE(1, NOPS, NOPS, NOPS, NOPS, GATE0);

    // ---- fused RoPE epilogue ----
    {
        const bool isf32 = dt_is_f32(fc);
        const float sc = (z == 0) ? (0.08838834764831845f * 1.4426950408889634f) : 1.0f;
        unsigned short* Cz = Cqk + (size_t)z * ((size_t)NB * SEQ * DIMN);
        const int crow0 = m0 + wm * 128 + fq * 4;
        const int ccol0 = n0 + wn * 64 + fr;
        #pragma unroll
        for (int mi = 0; mi < 8; mi++) {
            #pragma unroll
            for (int ni = 0; ni < 4; ni++) {
                const int col = ccol0 + ni * 16;
                const int j = (col & (DH - 1)) >> 1;
                size_t base = (size_t)(crow0 + mi * 16) * DIMN + col;
                #pragma unroll
                for (int r = 0; r < 4; r++) {
                    const int sr = (crow0 + mi * 16 + r) & (SEQ - 1);
                    float c, s;
                    if (isf32) {
                        c = ((const float*)fc)[sr * 64 + j];
                        s = ((const float*)fs)[sr * 64 + j];
                    } else {
                        c = b2f(((const unsigned short*)fc)[sr * 64 + j]);
                        s = b2f(((const unsigned short*)fs)[sr * 64 + j]);
                    }
                    c *= sc; s *= sc;
                    float v = acc[mi][ni][r];
                    float p = __shfl_xor(v, 1, 64);
                    float o = (col & 1) ? (p * s + v * c) : (v * c - p * s);
                    Cz[base + (size_t)r * DIMN] = f2b(o);
                }
            }
        }
    }
}

// =====================================================================
// 128x256 8-phase V GEMM with transposed epilogue. grid (8,32) = 256 blocks.
// =====================================================================
#define VNT 32   // K-tiles of 64

__global__ __launch_bounds__(512, 2) void gemm128_v(
    const unsigned short* __restrict__ A,
    const unsigned short* __restrict__ Bw,   // Wv (bf16)
    unsigned short* __restrict__ vT)
{
    __shared__ alignas(16) unsigned short sA[2][8192];    // [dbuf][128][64]
    __shared__ alignas(16) unsigned short sB[3][16384];   // [3ring][256][64]

    const int fid = blockIdx.y * 8 + blockIdx.x;
    const int sid = (fid & 7) * 32 + (fid >> 3);
    const int bx = sid & 7, by = sid >> 3;           // by 0..31
    const int n0 = bx << 8, m0 = by << 7;

    const int tid  = threadIdx.x;
    const int lane = tid & 63, wave = tid >> 6;
    const int wm = wave >> 2, wn = wave & 3;         // 2M x 4N, per-wave 64x64
    const int fr = lane & 15, fq = lane >> 4;

    const int srow = tid >> 3, sslot = tid & 7;
    const unsigned short* gA_base = A  + (size_t)(m0 + srow) * DIMN + ((sslot ^ (srow & 7)) << 3);
    const unsigned short* gB_base = Bw + (size_t)(n0 + srow) * DIMN + ((sslot ^ (srow & 7)) << 3);

    const int arow = wm * 64 + fr;
    const int brow = wn * 64 + fr;

    f32x4 acc[4][4];
    #pragma unroll
    for (int i = 0; i < 4; i++)
        #pragma unroll
        for (int j = 0; j < 4; j++)
            acc[i][j] = (f32x4){0.f, 0.f, 0.f, 0.f};

#define VSA(t, pa) do { \
    const unsigned short* g_ = gA_base + (size_t)(t) * 64; \
    unsigned short* l_ = &sA[pa][0] + tid * 8; \
    gload_lds16(g_, l_); \
    gload_lds16(g_ + (size_t)(64 * DIMN), l_ + 4096); \
} while (0)
#define VSB_H(h, t, tb) do { \
    const unsigned short* g_ = gB_base + (size_t)((h) * 128) * DIMN + (size_t)(t) * 64; \
    unsigned short* l_ = &sB[tb][(h) * 8192] + tid * 8; \
    gload_lds16(g_, l_); \
    gload_lds16(g_ + (size_t)(64 * DIMN), l_ + 4096); \
} while (0)

#define VLOAD_AF(pa) do { \
    _Pragma("unroll") \
    for (int mi_ = 0; mi_ < 4; mi_++) { \
        const int ra_ = arow + mi_ * 16; \
        _Pragma("unroll") \
        for (int kc_ = 0; kc_ < 2; kc_++) \
            af[mi_][kc_] = *(const bf16x8_a*)&sA[pa][(ra_ << 6) + (((kc_ * 4 + fq) ^ (ra_ & 7)) << 3)]; \
    } \
} while (0)
#define VLOAD_BF(dst, tb, rofs) do { \
    _Pragma("unroll") \
    for (int ni_ = 0; ni_ < 2; ni_++) { \
        const int rb_ = brow + (rofs) + ni_ * 16; \
        _Pragma("unroll") \
        for (int kc_ = 0; kc_ < 2; kc_++) \
            dst[ni_][kc_] = *(const bf16x8_a*)&sB[tb][(rb_ << 6) + (((kc_ * 4 + fq) ^ (rb_ & 7)) << 3)]; \
    } \
} while (0)

#define VMFMA(AF, BF, NBASE) do { \
    _Pragma("unroll") \
    for (int mi_ = 0; mi_ < 4; mi_++) \
    _Pragma("unroll") \
    for (int ni_ = 0; ni_ < 2; ni_++) \
    _Pragma("unroll") \
    for (int kc_ = 0; kc_ < 2; kc_++) \
        acc[mi_][(NBASE) + ni_] = __builtin_amdgcn_mfma_f32_16x16x32_bf16( \
            AF[mi_][kc_], BF[ni_][kc_], acc[mi_][(NBASE) + ni_], 0, 0, 0); \
} while (0)

#define VKT(PA, TB, T2, SA_, SB0_, SB1_, GATE) do { \
    VLOAD_AF(PA); \
    VLOAD_BF(bfA, TB, 0); \
    SA_; SB0_; \
    asm volatile("s_waitcnt lgkmcnt(8)"); \
    __builtin_amdgcn_s_barrier(); \
    asm volatile("s_waitcnt lgkmcnt(0)"); \
    __builtin_amdgcn_s_setprio(1); \
    VMFMA(af, bfA, 0); \
    __builtin_amdgcn_s_setprio(0); \
    __builtin_amdgcn_s_barrier(); \
    VLOAD_BF(bfB, TB, 32); \
    SB1_; \
    __builtin_amdgcn_s_barrier(); \
    asm volatile("s_waitcnt lgkmcnt(0)"); \
    __builtin_amdgcn_s_setprio(1); \
    VMFMA(af, bfB, 2); \
    __builtin_amdgcn_s_setprio(0); \
    GATE; \
    __builtin_amdgcn_s_barrier(); \
} while (0)

    VSA(0, 0);
    VSB_H(0, 0, 0); VSB_H(1, 0, 0);
    VSB_H(0, 1, 1); VSB_H(1, 1, 1);
    asm volatile("s_waitcnt vmcnt(4)");
    __builtin_amdgcn_s_barrier();

    bf16x8 af[4][2], bfA[2][2], bfB[2][2];

    for (int t = 0; t < VNT - 2; ++t) {
        const int PA = t & 1, TB = t % 3, T2 = (t + 2) % 3;
        VKT(PA, TB, T2,
            VSA(t + 1, PA ^ 1),
            VSB_H(0, t + 2, T2),
            VSB_H(1, t + 2, T2),
            GATE4);
    }
    VKT(0, (VNT - 2) % 3, 0, VSA(VNT - 1, 1), NOPS, NOPS, GATE0);
    VKT(1, (VNT - 1) % 3, 0, NOPS, NOPS, NOPS, NOPS);

    // ---- transposed epilogue: row = s (within batch), col = e ----
    {
        const int grow0 = m0 + wm * 64 + fq * 4;
        const int ccol0 = n0 + wn * 64 + fr;
        #pragma unroll
        for (int mi = 0; mi < 4; mi++) {
            const int grow = grow0 + mi * 16;
            const int bb = grow >> 11;            // row -> batch (SEQ=2048)
            const int ss = grow & (SEQ - 1);
            unsigned short* Vb = vT + (size_t)bb * SEQ * DIMN;
            #pragma unroll
            for (int ni = 0; ni < 4; ni++) {
                const int col = ccol0 + ni * 16;
                ushort4 w;
                w.x = f2b(acc[mi][ni][0]);
                w.y = f2b(acc[mi][ni][1]);
                w.z = f2b(acc[mi][ni][2]);
                w.w = f2b(acc[mi][ni][3]);
                *(ushort4_a*)(Vb + (size_t)col * SEQ + ss) = w;
            }
        }
    }
}

// =====================================================================
// 128x256 8-phase OUT-PROJECTION GEMM. grid (8,16,2) = 256 blocks.
// =====================================================================
__global__ __launch_bounds__(512, 2) void gemm128_o(
    const unsigned short* __restrict__ Act,
    const unsigned short* __restrict__ Bw,    // Wo (bf16)
    void* __restrict__ Cout,
    const void* __restrict__ dtp)
{
    __shared__ alignas(16) unsigned short sA[2][8192];    // [dbuf][128][64]
    __shared__ alignas(16) unsigned short sB[3][16384];   // [3ring][256][64]

    const bool cf32 = dt_is_f32(dtp);
    const long long SD = (long long)SEQ * DIMN;

    const int fid = (blockIdx.z * 16 + blockIdx.y) * 8 + blockIdx.x;
    const int sid = (fid & 7) * 32 + (fid >> 3);
    const int bx = sid & 7, rest = sid >> 3;
    const int by = rest & 15, z = rest >> 4;
    const int n0 = bx << 8, m0 = by << 7;

    const int tid  = threadIdx.x;
    const int lane = tid & 63, wave = tid >> 6;
    const int wm = wave >> 2, wn = wave & 3;         // 2M x 4N, per-wave 64x64
    const int fr = lane & 15, fq = lane >> 4;

    const int srow = tid >> 3, sslot = tid & 7;
    const unsigned short* gA_base = Act + (size_t)z * SD + (size_t)(m0 + srow) * DIMN + ((sslot ^ (srow & 7)) << 3);
    const unsigned short* gB_base = Bw + (size_t)(n0 + srow) * DIMN + ((sslot ^ (srow & 7)) << 3);

    const int arow = wm * 64 + fr;
    const int brow = wn * 64 + fr;

    f32x4 acc[4][4];
    #pragma unroll
    for (int i = 0; i < 4; i++)
        #pragma unroll
        for (int j = 0; j < 4; j++)
            acc[i][j] = (f32x4){0.f, 0.f, 0.f, 0.f};

    VSA(0, 0);
    VSB_H(0, 0, 0); VSB_H(1, 0, 0);
    VSB_H(0, 1, 1); VSB_H(1, 1, 1);
    asm volatile("s_waitcnt vmcnt(4)");
    __builtin_amdgcn_s_barrier();

    bf16x8 af[4][2], bfA[2][2], bfB[2][2];

    for (int t = 0; t < VNT - 2; ++t) {
        const int PA = t & 1, TB = t % 3, T2 = (t + 2) % 3;
        VKT(PA, TB, T2,
            VSA(t + 1, PA ^ 1),
            VSB_H(0, t + 2, T2),
            VSB_H(1, t + 2, T2),
            GATE4);
    }
    VKT(0, (VNT - 2) % 3, 0, VSA(VNT - 1, 1), NOPS, NOPS, GATE0);
    VKT(1, (VNT - 1) % 3, 0, NOPS, NOPS, NOPS, NOPS);

    {
        const int crow0 = m0 + wm * 64 + fq * 4;
        const int ccol0 = n0 + wn * 64 + fr;
        #pragma unroll
        for (int mi = 0; mi < 4; mi++)
            #pragma unroll
            for (int ni = 0; ni < 4; ni++) {
                size_t base = (size_t)(crow0 + mi * 16) * DIMN + (ccol0 + ni * 16);
                if (cf32) {
                    float* Cz = (float*)Cout + (size_t)z * SD;
                    #pragma unroll
                    for (int r = 0; r < 4; r++)
                        Cz[base + (size_t)r * DIMN] = acc[mi][ni][r];
                } else {
                    unsigned short* Cz = (unsigned short*)Cout + (size_t)z * SD;
                    #pragma unroll
                    for (int r = 0; r < 4; r++)
                        Cz[base + (size_t)r * DIMN] = f2b(acc[mi][ni][r]);
                }
            }
    }
}

// =====================================================================
extern "C" void kernel_launch(void* const* d_in, const int* in_sizes, int n_in,
                              void* d_out, int out_size, void* d_ws, size_t ws_size,
                              hipStream_t stream)
{
    const void* x  = d_in[0];
    const void* Wq = d_in[1];
    const void* Wk = d_in[2];
    const void* Wv = d_in[3];
    const void* Wo = d_in[4];
    const void* fc = d_in[5];
    const void* fs = d_in[6];

    const size_t NX = (size_t)NB * SEQ * DIMN;   // 8.39M elems
    const size_t NW = (size_t)DIMN * DIMN;       // 4.19M elems
    unsigned short* wsp = (unsigned short*)d_ws;
    dim3 blk(256);
    const long long SD = (long long)SEQ * DIMN;
    dim3 gcx((int)(NX / 8 / 256));               // convert grid for x-sized bufs
    dim3 gcw((int)(NW / 8 / 256));               // convert grid for W-sized bufs
    dim3 gr((int)(NX / 8 / 256), 2, 1);          // rope (non-fused path)
    dim3 gt(SEQ / 32, DIMN / 32, NB);            // transpose (non-fused path)
    dim3 gf(NQT * NBH, 1, 1);                    // flash (1D, pair-balanced qt)
    dim3 gp(DIMN / 128, DIMN / 128, NB);         // out gemm (non-fused path)

    const bool fused = ws_size >= (NX + 3 * NW + 3 * NX) * sizeof(unsigned short);

    if (fused) {
        // layout: xb | wqkv(3W) | q,k,vT.  ctxT<-wqkv, wob<-wqkv+NX
        unsigned short* xb    = wsp;
        unsigned short* wqkv  = xb + NX;
        unsigned short* q_lin = wqkv + 3 * NW;
        unsigned short* k_lin = q_lin + NX;
        unsigned short* vT2   = k_lin + NX;      // V written transposed directly
        unsigned short* ctxT  = wqkv;
        unsigned short* wob   = wqkv + NX;

        dim3 gc4((NX8 + 3 * NW8) / 256);
        convert4_kernel<<<gc4, blk, 0, stream>>>(x, Wq, Wk, Wv, xb, wqkv, fc);

        dim3 g256(8, 16, 2);                     // Q,K (rope fused in epilogue)
        gemm256_qkv<<<g256, dim3(512), 0, stream>>>(xb, wqkv, q_lin, fc, fs);
        dim3 gv(8, 32, 1);                       // V: 256 blocks = 1 half round
        gemm128_v<<<gv, dim3(512), 0, stream>>>(xb, wqkv + 2 * NW, vT2);

        flash_kernel<<<gf, blk, 0, stream>>>(q_lin, k_lin, vT2, ctxT);

        convert_kernel<<<gcw, blk, 0, stream>>>(Wo, wob, (int)(NW / 8), fc);
        dim3 go(8, 16, 2);                       // out-proj: 256 blocks = 1 round
        gemm128_o<<<go, dim3(512), 0, stream>>>(ctxT, wob, d_out, fc);
    } else {
        // layout: xb | wb | q | k | v.  vT<-xb, ctxT<-v_lin, wob<-wb   (75.5 MB)
        unsigned short* xb    = wsp;
        unsigned short* wb    = xb + NX;
        unsigned short* q_lin = wb + NW;
        unsigned short* k_lin = q_lin + NX;
        unsigned short* v_lin = k_lin + NX;
        unsigned short* vT    = xb;
        unsigned short* ctxT  = v_lin;

        convert_kernel<<<gcx, blk, 0, stream>>>(x, xb, (int)(NX / 8), fc);
        dim3 g1(DIMN / 128, (NB * SEQ) / 128, 1);
        convert_kernel<<<gcw, blk, 0, stream>>>(Wq, wb, (int)(NW / 8), fc);
        gemm_bt<<<g1, blk, 0, stream>>>(xb, wb, q_lin, fc, 0,
            DIMN, DIMN, DIMN, DIMN, 1, 0, 0, 0, 0, 0, 0, 1.0f);
        convert_kernel<<<gcw, blk, 0, stream>>>(Wk, wb, (int)(NW / 8), fc);
        gemm_bt<<<g1, blk, 0, stream>>>(xb, wb, k_lin, fc, 0,
            DIMN, DIMN, DIMN, DIMN, 1, 0, 0, 0, 0, 0, 0, 1.0f);
        convert_kernel<<<gcw, blk, 0, stream>>>(Wv, wb, (int)(NW / 8), fc);
        gemm_bt<<<g1, blk, 0, stream>>>(xb, wb, v_lin, fc, 0,
            DIMN, DIMN, DIMN, DIMN, 1, 0, 0, 0, 0, 0, 0, 1.0f);

        rope_kernel<<<gr, blk, 0, stream>>>(q_lin, k_lin, fc, fs);
        transpose_kernel<<<gt, blk, 0, stream>>>(v_lin, vT);
        flash_kernel<<<gf, blk, 0, stream>>>(q_lin, k_lin, vT, ctxT);

        convert_kernel<<<gcw, blk, 0, stream>>>(Wo, wb, (int)(NW / 8), fc);
        gemm_bt<<<gp, blk, 0, stream>>>(ctxT, wb, d_out, fc, 1,
            SEQ, SEQ, DIMN, DIMN, 1, SD, 0, 0, 0, SD, 0, 1.0f);
    }
}

// Round 7
// 380.183 us; speedup vs baseline: 1.0415x; 1.0415x over previous
//
#include <hip/hip_runtime.h>
#include <cstdint>
#include <cstddef>

#define DIMN 2048
#define SEQ  2048
#define NB   2
#define NH   16
#define DH   128
#define NQT  (SEQ / 128)    // 16 q-tiles
#define NBH  (NB * NH)      // 32

typedef __bf16 bf16x8 __attribute__((ext_vector_type(8)));
typedef float  f32x4  __attribute__((ext_vector_type(4)));
typedef bf16x8 __attribute__((may_alias)) bf16x8_a;
typedef ushort4 __attribute__((may_alias)) ushort4_a;
typedef float4 __attribute__((may_alias)) float4_a;

// ---- bf16 <-> f32 helpers on raw ushort storage (RNE, matches np/jnp) ----
__device__ __forceinline__ float b2f(unsigned short b) {
    unsigned u = ((unsigned)b) << 16; float f; __builtin_memcpy(&f, &u, 4); return f;
}
__device__ __forceinline__ unsigned short f2b(float f) {
    unsigned u; __builtin_memcpy(&u, &f, 4);
    u = (u + 0x7FFFu + ((u >> 16) & 1u)) >> 16;
    return (unsigned short)u;
}
__device__ __forceinline__ __bf16 f2bf(float f) {
    unsigned short us = f2b(f); __bf16 h; __builtin_memcpy(&h, &us, 2); return h;
}

// dtype flag: freqs_cos[0]==1.0 -> fp32 word0 = 0x3F800000 (bf16 would be 0x3F803F80)
__device__ __forceinline__ bool dt_is_f32(const void* fc) {
    return ((const unsigned int*)fc)[0] == 0x3F800000u;
}

// async global->LDS, 16B per lane (LDS dest = wave-uniform base + lane*16)
__device__ __forceinline__ void gload_lds16(const unsigned short* g, unsigned short* l) {
    __builtin_amdgcn_global_load_lds(
        (const __attribute__((address_space(1))) void*)g,
        (__attribute__((address_space(3))) void*)l,
        16, 0, 0);
}

// ============== convert fp32 (or bf16 passthrough) -> bf16, 8 elems/thread ==============
__device__ __forceinline__ void conv8(const void* in, unsigned short* out, size_t i, bool isf32) {
    if (isf32) {
        const float* p = (const float*)in + i * 8;
        float4 lo = *(const float4_a*)p;
        float4 hi = *(const float4_a*)(p + 4);
        ushort4 a, b;
        a.x = f2b(lo.x); a.y = f2b(lo.y); a.z = f2b(lo.z); a.w = f2b(lo.w);
        b.x = f2b(hi.x); b.y = f2b(hi.y); b.z = f2b(hi.z); b.w = f2b(hi.w);
        *(ushort4_a*)(out + i * 8)     = a;
        *(ushort4_a*)(out + i * 8 + 4) = b;
    } else {
        const ushort4* p = (const ushort4*)((const char*)in + i * 16);
        *(ushort4_a*)(out + i * 8)     = p[0];
        *(ushort4_a*)(out + i * 8 + 4) = p[1];
    }
}

__global__ void convert_kernel(const void* __restrict__ in, unsigned short* __restrict__ out,
                               int n8, const void* __restrict__ dt)
{
    const bool isf32 = dt_is_f32(dt);
    int i = blockIdx.x * 256 + threadIdx.x;
    if (i >= n8) return;
    conv8(in, out, (size_t)i, isf32);
}

// fused convert of x, Wq, Wk, Wv in one launch (fused path only)
#define NX8 1048576   // NB*SEQ*DIMN/8
#define NW8 524288    // DIMN*DIMN/8
__global__ void convert4_kernel(const void* __restrict__ x,  const void* __restrict__ wq,
                                const void* __restrict__ wk, const void* __restrict__ wv,
                                unsigned short* __restrict__ xb,
                                unsigned short* __restrict__ wqkv,
                                const void* __restrict__ dt)
{
    const bool isf32 = dt_is_f32(dt);
    int i = blockIdx.x * 256 + threadIdx.x;
    if (i < NX8) { conv8(x, xb, (size_t)i, isf32); return; }
    int j = i - NX8;
    int w = j / NW8, o = j - w * NW8;
    const void* src = (w == 0) ? wq : (w == 1) ? wk : wv;
    conv8(src, wqkv + (size_t)w * DIMN * DIMN, (size_t)o, isf32);
}

// =====================================================================
// "bt" GEMM (m97 128x128 structure), kept for non-fused path.
// =====================================================================
__global__ __launch_bounds__(256, 2) void gemm_bt(
    const unsigned short* __restrict__ A, const unsigned short* __restrict__ B,
    void* __restrict__ C, const void* __restrict__ dt, int cmode,
    int K, int lda, int ldb, int ldc, int Hz,
    long long sAb, long long sAh, long long sBb, long long sBh,
    long long sCb, long long sCh, float scale)
{
    const bool cf32 = cmode && dt_is_f32(dt);

    const int gx = gridDim.x, gy = gridDim.y;
    const int nwg = gx * gy * gridDim.z;
    const int fid = (blockIdx.z * gy + blockIdx.y) * gx + blockIdx.x;
    const int qq = nwg >> 3, rr = nwg & 7, xc = fid & 7, rem = fid >> 3;
    const int sid = (xc < rr ? xc * (qq + 1) : rr * (qq + 1) + (xc - rr) * qq) + rem;
    const int bx = sid % gx;
    const int t_ = sid / gx;
    const int by = t_ % gy;
    const int z  = t_ / gy;

    int zb = z / Hz, zh = z - zb * Hz;
    const unsigned short* Az = A + zb * sAb + zh * sAh;
    const unsigned short* Bz = B + zb * sBb + zh * sBh;
    const long long coffz = zb * sCb + zh * sCh;
    const int m0 = by * 128, n0 = bx * 128;

    __shared__ alignas(16) unsigned short sA[128 * 32];
    __shared__ alignas(16) unsigned short sB[128 * 32];

    const int tid  = threadIdx.x;
    const int lane = tid & 63, wave = tid >> 6;
    const int waveM = wave >> 1, waveN = wave & 1;

    const int rowA = tid >> 2;          // 0..63
    const int c8   = (tid & 3) << 3;    // 0,8,16,24
    const unsigned short* gA0 = Az + (size_t)(m0 + rowA)      * lda + c8;
    const unsigned short* gA1 = Az + (size_t)(m0 + rowA + 64) * lda + c8;
    const unsigned short* gB0 = Bz + (size_t)(n0 + rowA)      * ldb + c8;
    const unsigned short* gB1 = Bz + (size_t)(n0 + rowA + 64) * ldb + c8;
    unsigned short* lA0 = sA + tid * 8;
    unsigned short* lA1 = sA + 2048 + tid * 8;
    unsigned short* lB0 = sB + tid * 8;
    unsigned short* lB1 = sB + 2048 + tid * 8;

    f32x4 acc[4][4];
    #pragma unroll
    for (int i = 0; i < 4; i++)
        #pragma unroll
        for (int j = 0; j < 4; j++)
            acc[i][j] = (f32x4){0.f, 0.f, 0.f, 0.f};

    const int fr = lane & 15, fq = lane >> 4;
    const int aoff = (waveM * 64 + fr) * 32 + fq * 8;
    const int boff = (waveN * 64 + fr) * 32 + fq * 8;

    for (int kt = 0; kt < K; kt += 32) {
        gload_lds16(gA0, lA0);
        gload_lds16(gA1, lA1);
        gload_lds16(gB0, lB0);
        gload_lds16(gB1, lB1);
        gA0 += 32; gA1 += 32; gB0 += 32; gB1 += 32;
        __syncthreads();

        bf16x8 af[4], bfr[4];
        #pragma unroll
        for (int mt = 0; mt < 4; mt++)
            af[mt] = *(const bf16x8_a*)(sA + aoff + mt * 16 * 32);
        #pragma unroll
        for (int nt = 0; nt < 4; nt++)
            bfr[nt] = *(const bf16x8_a*)(sB + boff + nt * 16 * 32);
        #pragma unroll
        for (int mt = 0; mt < 4; mt++)
            #pragma unroll
            for (int nt = 0; nt < 4; nt++)
                acc[mt][nt] = __builtin_amdgcn_mfma_f32_16x16x32_bf16(
                    af[mt], bfr[nt], acc[mt][nt], 0, 0, 0);
        __syncthreads();
    }

    const int crow0 = m0 + waveM * 64 + fq * 4;
    const int ccol0 = n0 + waveN * 64 + fr;
    #pragma unroll
    for (int mt = 0; mt < 4; mt++)
        #pragma unroll
        for (int nt = 0; nt < 4; nt++) {
            size_t base = (size_t)(crow0 + mt * 16) * ldc + (ccol0 + nt * 16);
            if (cf32) {
                float* Cz = (float*)C + coffz;
                #pragma unroll
                for (int r = 0; r < 4; r++)
                    Cz[base + (size_t)r * ldc] = acc[mt][nt][r] * scale;
            } else {
                unsigned short* Cz = (unsigned short*)C + coffz;
                #pragma unroll
                for (int r = 0; r < 4; r++)
                    Cz[base + (size_t)r * ldc] = f2b(acc[mt][nt][r] * scale);
            }
        }
}

// ============== RoPE body (Q pre-scaled by log2e/sqrt(DH) for exp2 softmax) ==============
__device__ __forceinline__ void rope_body(unsigned short* p, int idx, float sc,
                                          const void* fc, const void* fs, bool isf32)
{
    int row = idx >> 8;                         // [0, NB*SEQ)
    int e   = (idx & 255) << 3;                 // feature 0..2047 step 8
    int s   = row & (SEQ - 1);
    int j0  = (e & (DH - 1)) >> 1;              // 4 pairs j0..j0+3
    float c[4], sn[4];
    #pragma unroll
    for (int t = 0; t < 4; t++) {
        if (isf32) {
            c[t]  = ((const float*)fc)[s * 64 + j0 + t] * sc;
            sn[t] = ((const float*)fs)[s * 64 + j0 + t] * sc;
        } else {
            c[t]  = b2f(((const unsigned short*)fc)[s * 64 + j0 + t]) * sc;
            sn[t] = b2f(((const unsigned short*)fs)[s * 64 + j0 + t]) * sc;
        }
    }
    size_t off = (size_t)row * DIMN + e;
    ushort4 a = *(ushort4_a*)(p + off);
    ushort4 b = *(ushort4_a*)(p + off + 4);
    float xs[8] = {b2f(a.x), b2f(a.y), b2f(a.z), b2f(a.w),
                   b2f(b.x), b2f(b.y), b2f(b.z), b2f(b.w)};
    ushort4 oa, ob;
    oa.x = f2b(xs[0] * c[0] - xs[1] * sn[0]);
    oa.y = f2b(xs[0] * sn[0] + xs[1] * c[0]);
    oa.z = f2b(xs[2] * c[1] - xs[3] * sn[1]);
    oa.w = f2b(xs[2] * sn[1] + xs[3] * c[1]);
    ob.x = f2b(xs[4] * c[2] - xs[5] * sn[2]);
    ob.y = f2b(xs[4] * sn[2] + xs[5] * c[2]);
    ob.z = f2b(xs[6] * c[3] - xs[7] * sn[3]);
    ob.w = f2b(xs[6] * sn[3] + xs[7] * c[3]);
    *(ushort4_a*)(p + off)     = oa;
    *(ushort4_a*)(p + off + 4) = ob;
}

// RoPE on q,k (non-fused path)
__global__ void rope_kernel(unsigned short* q, unsigned short* k,
                            const void* __restrict__ fc,
                            const void* __restrict__ fs)
{
    const bool isf32 = dt_is_f32(fc);
    int idx = blockIdx.x * 256 + threadIdx.x;
    unsigned short* p = blockIdx.y ? k : q;
    const float sc = blockIdx.y ? 1.0f : (0.08838834764831845f * 1.4426950408889634f);
    rope_body(p, idx, sc, fc, fs, isf32);
}

// RoPE on q,k + Wo convert in ONE launch (fused path): y=0 q, y=1 k, y=2 conv Wo
__global__ void rope_convwo_kernel(unsigned short* q, unsigned short* k,
                                   const void* __restrict__ wo,
                                   unsigned short* __restrict__ wob,
                                   const void* __restrict__ fc,
                                   const void* __restrict__ fs)
{
    const bool isf32 = dt_is_f32(fc);
    int idx = blockIdx.x * 256 + threadIdx.x;
    if (blockIdx.y == 2) {
        if (idx < NW8) conv8(wo, wob, (size_t)idx, isf32);
        return;
    }
    unsigned short* p = blockIdx.y ? k : q;
    const float sc = blockIdx.y ? 1.0f : (0.08838834764831845f * 1.4426950408889634f);
    rope_body(p, idx, sc, fc, fs, isf32);
}

// ============== per-batch 2048x2048 transpose (non-fused path only) ==============
__global__ void transpose_kernel(const unsigned short* __restrict__ in,
                                 unsigned short* __restrict__ out)
{
    __shared__ unsigned short tile[32][33];
    int b = blockIdx.z;
    const unsigned short* ib = in + (size_t)b * SEQ * DIMN;
    unsigned short*       ob = out + (size_t)b * SEQ * DIMN;
    int t0 = blockIdx.x << 5, i0 = blockIdx.y << 5;
    int c = threadIdx.x & 31, r0 = threadIdx.x >> 5;
    for (int r = r0; r < 32; r += 8)
        tile[r][c] = ib[(size_t)(t0 + r) * DIMN + i0 + c];
    __syncthreads();
    for (int r = r0; r < 32; r += 8)
        ob[(size_t)(i0 + r) * SEQ + t0 + c] = tile[c][r];
}

// =====================================================================
// Fused flash attention (causal). Swapped QK^T; exp2-domain softmax.
// LDS 48 KB -> 3 blocks/CU: K double-buffered (async DMA, hidden),
// V single-buffered (staged at iter end), P OVERLAID into dead sK[cur].
// =====================================================================
__global__ __launch_bounds__(256, 2) void flash_kernel(
    const unsigned short* __restrict__ q_lin,
    const unsigned short* __restrict__ k_lin,
    const unsigned short* __restrict__ vTg,
    unsigned short* __restrict__ ctxT)
{
    __shared__ alignas(16) unsigned short sK[2][64 * 128];   // 32 KB; sK[cur] doubles as P
    __shared__ alignas(16) unsigned short sV[128 * 64];      // 16 KB, single buffer

    const int idx  = blockIdx.x;                 // [0, NQT*NBH)
    const int slot = idx >> 5;
    const int qt   = (slot < 8) ? (15 - slot) : (slot - 8);  // pair-balanced
    const int z    = idx & (NBH - 1);
    const int b    = z >> 4, h = z & 15;

    const unsigned short* Qg = q_lin + ((size_t)(b * SEQ + qt * 128)) * DIMN + h * DH;
    const unsigned short* Kg = k_lin + (size_t)b * SEQ * DIMN + h * DH;
    const unsigned short* Vg = vTg  + (size_t)b * SEQ * DIMN + (size_t)h * DH * SEQ;
    unsigned short*       Cg = ctxT + (size_t)b * SEQ * DIMN + (size_t)h * DH * SEQ;

    const int tid  = threadIdx.x;
    const int lane = tid & 63, wave = tid >> 6;
    const int fr = lane & 15, fq = lane >> 4;

    // Q fragments (B-operand): row = wave*32 + qq*16 + fr, k = kt*32 + fq*8 + j
    bf16x8 qf[2][4];
    #pragma unroll
    for (int mt = 0; mt < 2; mt++)
        #pragma unroll
        for (int kt = 0; kt < 4; kt++)
            qf[mt][kt] = *(const bf16x8_a*)(Qg + (size_t)(wave * 32 + mt * 16 + fr) * DIMN + kt * 32 + fq * 8);

    f32x4 o_acc[2][8];
    #pragma unroll
    for (int mt = 0; mt < 2; mt++)
        #pragma unroll
        for (int nt = 0; nt < 8; nt++)
            o_acc[mt][nt] = (f32x4){0.f, 0.f, 0.f, 0.f};
    float m_st[2], l_st[2];
    m_st[0] = m_st[1] = -1e30f;
    l_st[0] = l_st[1] = 0.f;

#define FSTAGE_K(pb, jn) do { \
    const unsigned short* Kt_ = Kg + (size_t)(jn) * 64 * DIMN; \
    _Pragma("unroll") \
    for (int i_ = 0; i_ < 4; i_++) { \
        int cc_ = tid + i_ * 256; int r_ = cc_ >> 4, c_ = cc_ & 15; \
        gload_lds16(Kt_ + (size_t)r_ * DIMN + ((c_ ^ (r_ & 7)) << 3), &sK[pb][cc_ * 8]); \
    } \
} while (0)
#define FSTAGE_V(jn) do { \
    const unsigned short* Vt_ = Vg + (jn) * 64; \
    _Pragma("unroll") \
    for (int i_ = 0; i_ < 4; i_++) { \
        int cc_ = tid + i_ * 256; int r_ = cc_ >> 3, c_ = cc_ & 7; \
        gload_lds16(Vt_ + (size_t)r_ * SEQ + ((c_ ^ (r_ & 7)) << 3), &sV[cc_ * 8]); \
    } \
} while (0)

    const int jmax = 2 * qt + 2;

    FSTAGE_K(0, 0);
    FSTAGE_V(0);

    for (int jt = 0; jt < jmax; jt++) {
        const int cur = jt & 1;
        if (jt + 1 < jmax) {
            FSTAGE_K(cur ^ 1, jt + 1);           // async into other K buffer
            asm volatile("s_waitcnt vmcnt(4)");  // K(jt)+V(jt) landed; K(jt+1) in flight
        } else {
            asm volatile("s_waitcnt vmcnt(0)");
        }
        __builtin_amdgcn_s_barrier();

        // S^T = K . Q^T : lane holds col q = qq*16+fr, rows t = tt*16+fq*4+r
        f32x4 sT[4][2];
        #pragma unroll
        for (int tt = 0; tt < 4; tt++)
            #pragma unroll
            for (int qq = 0; qq < 2; qq++)
                sT[tt][qq] = (f32x4){0.f, 0.f, 0.f, 0.f};
        __builtin_amdgcn_s_setprio(1);
        #pragma unroll
        for (int kt = 0; kt < 4; kt++) {
            bf16x8 kf[4];
            #pragma unroll
            for (int tt = 0; tt < 4; tt++) {
                const int row = tt * 16 + fr;
                kf[tt] = *(const bf16x8_a*)&sK[cur][row * 128 + (((kt * 4 + fq) ^ (fr & 7)) << 3)];
            }
            #pragma unroll
            for (int tt = 0; tt < 4; tt++)
                #pragma unroll
                for (int qq = 0; qq < 2; qq++)
                    sT[tt][qq] = __builtin_amdgcn_mfma_f32_16x16x32_bf16(
                        kf[tt], qf[qq][kt], sT[tt][qq], 0, 0, 0);
        }
        __builtin_amdgcn_s_setprio(0);

        if (jt >= 2 * qt) {
            #pragma unroll
            for (int tt = 0; tt < 4; tt++)
                #pragma unroll
                for (int qq = 0; qq < 2; qq++)
                    #pragma unroll
                    for (int r = 0; r < 4; r++) {
                        int trel = jt * 64 + tt * 16 + fq * 4 + r - qt * 128;
                        int qrow = wave * 32 + qq * 16 + fr;
                        if (trel > qrow) sT[tt][qq][r] = -1e30f;
                    }
        }

        // per-q max: 15 in-lane fmax + 2 shfls
        float pm[2];
        #pragma unroll
        for (int qq = 0; qq < 2; qq++) {
            float rm = sT[0][qq][0];
            #pragma unroll
            for (int tt = 0; tt < 4; tt++)
                #pragma unroll
                for (int r = 0; r < 4; r++)
                    if (tt || r) rm = fmaxf(rm, sT[tt][qq][r]);
            rm = fmaxf(rm, __shfl_xor(rm, 16, 64));
            rm = fmaxf(rm, __shfl_xor(rm, 32, 64));
            pm[qq] = rm;
        }

        // all waves done reading sK[cur] -> it becomes the P buffer
        __builtin_amdgcn_s_barrier();
        unsigned short* sPp = &sK[cur][0];

        bool need = (pm[0] > m_st[0] + 8.0f) || (pm[1] > m_st[1] + 8.0f);
        if (__any((int)need)) {
            float alc[2];
            #pragma unroll
            for (int qq = 0; qq < 2; qq++) {
                float mn = fmaxf(m_st[qq], pm[qq]);
                alc[qq] = __builtin_amdgcn_exp2f(m_st[qq] - mn);
                m_st[qq] = mn;
                l_st[qq] *= alc[qq];
            }
            #pragma unroll
            for (int mt = 0; mt < 2; mt++) {
                float a[4];
                #pragma unroll
                for (int r = 0; r < 4; r++)
                    a[r] = __shfl(alc[mt], fq * 4 + r, 64);
                #pragma unroll
                for (int nt = 0; nt < 8; nt++)
                    #pragma unroll
                    for (int r = 0; r < 4; r++)
                        o_acc[mt][nt][r] *= a[r];
            }
        }

        // P = exp2(S^T - m) -> packed b64 stores into overlay
        float ps[2] = {0.f, 0.f};
        #pragma unroll
        for (int qq = 0; qq < 2; qq++) {
            const int qrow = wave * 32 + qq * 16 + fr;
            #pragma unroll
            for (int tt = 0; tt < 4; tt++) {
                float p0 = __builtin_amdgcn_exp2f(sT[tt][qq][0] - m_st[qq]);
                float p1 = __builtin_amdgcn_exp2f(sT[tt][qq][1] - m_st[qq]);
                float p2 = __builtin_amdgcn_exp2f(sT[tt][qq][2] - m_st[qq]);
                float p3 = __builtin_amdgcn_exp2f(sT[tt][qq][3] - m_st[qq]);
                ps[qq] += (p0 + p1) + (p2 + p3);
                ushort4 w;
                w.x = f2b(p0); w.y = f2b(p1); w.z = f2b(p2); w.w = f2b(p3);
                const int cpos = (tt * 2 + (fq >> 1)) ^ (qrow & 7);
                *(ushort4_a*)(sPp + qrow * 64 + cpos * 8 + (fq & 1) * 4) = w;
            }
        }
        #pragma unroll
        for (int qq = 0; qq < 2; qq++) {
            float s = ps[qq];
            s += __shfl_xor(s, 16, 64);
            s += __shfl_xor(s, 32, 64);
            l_st[qq] += s;
        }

        // O += P . V
        __builtin_amdgcn_s_setprio(1);
        #pragma unroll
        for (int kt = 0; kt < 2; kt++) {
            bf16x8 pf[2], vf[8];
            #pragma unroll
            for (int mt = 0; mt < 2; mt++) {
                int prow = wave * 32 + mt * 16 + fr;
                int cw   = (kt * 4 + fq) ^ (prow & 7);
                pf[mt] = *(const bf16x8_a*)(sPp + prow * 64 + (cw << 3));
            }
            #pragma unroll
            for (int nt = 0; nt < 8; nt++) {
                const int row = nt * 16 + fr;
                vf[nt] = *(const bf16x8_a*)&sV[row * 64 + (((kt * 4 + fq) ^ (fr & 7)) << 3)];
            }
            #pragma unroll
            for (int mt = 0; mt < 2; mt++)
                #pragma unroll
                for (int nt = 0; nt < 8; nt++)
                    o_acc[mt][nt] = __builtin_amdgcn_mfma_f32_16x16x32_bf16(
                        pf[mt], vf[nt], o_acc[mt][nt], 0, 0, 0);
        }
        __builtin_amdgcn_s_setprio(0);
        __builtin_amdgcn_s_barrier();                // all waves done reading sV & P
        if (jt + 1 < jmax) FSTAGE_V(jt + 1);         // overwrite sV now
    }

    // epilogue: O /= l (broadcast col-wise l to row layout), write ctxT[dh][s]
    #pragma unroll
    for (int mt = 0; mt < 2; mt++) {
        float invc = 1.0f / l_st[mt];
        float inv[4];
        #pragma unroll
        for (int r = 0; r < 4; r++)
            inv[r] = __shfl(invc, fq * 4 + r, 64);
        const int s0 = qt * 128 + wave * 32 + mt * 16 + fq * 4;
        #pragma unroll
        for (int nt = 0; nt < 8; nt++) {
            ushort4 w;
            w.x = f2b(o_acc[mt][nt][0] * inv[0]);
            w.y = f2b(o_acc[mt][nt][1] * inv[1]);
            w.z = f2b(o_acc[mt][nt][2] * inv[2]);
            w.w = f2b(o_acc[mt][nt][3] * inv[3]);
            int dh = nt * 16 + fr;
            *(ushort4_a*)(Cg + (size_t)dh * SEQ + s0) = w;
        }
    }
}

// =====================================================================
// 256x256 8-phase Q/K GEMM (T1..T5), plain bf16 epilogue (RoPE fusion
// REVERTED: the epilogue's scattered per-element table reads were a
// +35 us TA-bound tail; see R6 post-mortem). grid (8,16,2) = 256 blocks.
// =====================================================================
#define NIT16 16   // K=2048 / 128 per iteration (2 K-tiles of 64)

__global__ __launch_bounds__(512, 2) void gemm256_qkv(
    const unsigned short* __restrict__ A,
    const unsigned short* __restrict__ Bw,
    unsigned short* __restrict__ Cqk)
{
    __shared__ alignas(16) unsigned short sA[2][16384];   // [dbuf][256 rows][64 cols]
    __shared__ alignas(16) unsigned short sB[2][16384];

    const int fid = (blockIdx.z * 16 + blockIdx.y) * 8 + blockIdx.x;
    const int sid = (fid & 7) * 32 + (fid >> 3);
    const int bx = sid & 7, by = (sid >> 3) & 15, z = sid >> 7;

    const unsigned short* Bz = Bw + (size_t)z * DIMN * DIMN;
    const int n0 = bx << 8, m0 = by << 8;

    const int tid  = threadIdx.x;
    const int lane = tid & 63, wave = tid >> 6;
    const int wm = wave >> 2, wn = wave & 3;
    const int fr = lane & 15, fq = lane >> 4;

    const int srow = tid >> 3, sslot = tid & 7;
    const unsigned short* gA_base = A  + (size_t)(m0 + srow) * DIMN + ((sslot ^ (srow & 7)) << 3);
    const unsigned short* gB_base = Bz + (size_t)(n0 + srow) * DIMN + ((sslot ^ (srow & 7)) << 3);

    const int arow = wm * 128 + fr;
    const int brow = wn * 64 + fr;

    f32x4 acc[8][4];
    #pragma unroll
    for (int i = 0; i < 8; i++)
        #pragma unroll
        for (int j = 0; j < 4; j++)
            acc[i][j] = (f32x4){0.f, 0.f, 0.f, 0.f};

#define STAGE_A(h, t, pb) do { \
    const unsigned short* g_ = gA_base + (size_t)((h) * 128) * DIMN + (size_t)(t) * 64; \
    unsigned short* l_ = &sA[pb][(h) * 8192] + tid * 8; \
    gload_lds16(g_, l_); \
    gload_lds16(g_ + (size_t)(64 * DIMN), l_ + 4096); \
} while (0)
#define STAGE_B(h, t, pb) do { \
    const unsigned short* g_ = gB_base + (size_t)((h) * 128) * DIMN + (size_t)(t) * 64; \
    unsigned short* l_ = &sB[pb][(h) * 8192] + tid * 8; \
    gload_lds16(g_, l_); \
    gload_lds16(g_ + (size_t)(64 * DIMN), l_ + 4096); \
} while (0)

#define LOAD_AF(dst, pb, rofs) do { \
    _Pragma("unroll") \
    for (int mi_ = 0; mi_ < 4; mi_++) { \
        const int ra_ = arow + (rofs) + mi_ * 16; \
        _Pragma("unroll") \
        for (int kc_ = 0; kc_ < 2; kc_++) \
            dst[mi_][kc_] = *(const bf16x8_a*)&sA[pb][(ra_ << 6) + (((kc_ * 4 + fq) ^ (ra_ & 7)) << 3)]; \
    } \
} while (0)
#define LOAD_BF(dst, pb, rofs) do { \
    _Pragma("unroll") \
    for (int ni_ = 0; ni_ < 2; ni_++) { \
        const int rb_ = brow + (rofs) + ni_ * 16; \
        _Pragma("unroll") \
        for (int kc_ = 0; kc_ < 2; kc_++) \
            dst[ni_][kc_] = *(const bf16x8_a*)&sB[pb][(rb_ << 6) + (((kc_ * 4 + fq) ^ (rb_ & 7)) << 3)]; \
    } \
} while (0)

#define MFMA4x2(AF, BF, MB, NBASE) do { \
    _Pragma("unroll") \
    for (int mi_ = 0; mi_ < 4; mi_++) \
    _Pragma("unroll") \
    for (int ni_ = 0; ni_ < 2; ni_++) \
    _Pragma("unroll") \
    for (int kc_ = 0; kc_ < 2; kc_++) \
        acc[(MB) + mi_][(NBASE) + ni_] = __builtin_amdgcn_mfma_f32_16x16x32_bf16( \
            AF[mi_][kc_], BF[ni_][kc_], acc[(MB) + mi_][(NBASE) + ni_], 0, 0, 0); \
} while (0)

#define GATE4 asm volatile("s_waitcnt vmcnt(4)")
#define GATE0 asm volatile("s_waitcnt vmcnt(0)")
#define NOPS  ((void)0)

#define KTILE(PB, SA0, SA1, SB0, SB1, GATE) do { \
    LOAD_AF(af0, PB, 0); \
    LOAD_BF(bf0, PB, 0); \
    SA0; \
    asm volatile("s_waitcnt lgkmcnt(8)"); \
    __builtin_amdgcn_s_barrier(); \
    asm volatile("s_waitcnt lgkmcnt(0)"); \
    __builtin_amdgcn_s_setprio(1); \
    MFMA4x2(af0, bf0, 0, 0); \
    __builtin_amdgcn_s_setprio(0); \
    __builtin_amdgcn_s_barrier(); \
    LOAD_BF(bf1, PB, 32); \
    SA1; \
    __builtin_amdgcn_s_barrier(); \
    asm volatile("s_waitcnt lgkmcnt(0)"); \
    __builtin_amdgcn_s_setprio(1); \
    MFMA4x2(af0, bf1, 0, 2); \
    __builtin_amdgcn_s_setprio(0); \
    __builtin_amdgcn_s_barrier(); \
    LOAD_AF(af1, PB, 64); \
    SB0; \
    __builtin_amdgcn_s_barrier(); \
    asm volatile("s_waitcnt lgkmcnt(0)"); \
    __builtin_amdgcn_s_setprio(1); \
    MFMA4x2(af1, bf1, 4, 2); \
    __builtin_amdgcn_s_setprio(0); \
    __builtin_amdgcn_s_barrier(); \
    SB1; \
    __builtin_amdgcn_s_barrier(); \
    __builtin_amdgcn_s_setprio(1); \
    MFMA4x2(af1, bf0, 4, 0); \
    __builtin_amdgcn_s_setprio(0); \
    GATE; \
    __builtin_amdgcn_s_barrier(); \
} while (0)

    STAGE_A(0, 0, 0); STAGE_A(1, 0, 0);
    STAGE_B(0, 0, 0); STAGE_B(1, 0, 0);
    STAGE_B(0, 1, 1); STAGE_B(1, 1, 1);
    asm volatile("s_waitcnt vmcnt(4)");
    __builtin_amdgcn_s_barrier();

    bf16x8 af0[4][2], af1[4][2], bf0[2][2], bf1[2][2];

    for (int it = 0; it < NIT16 - 1; ++it) {
        const int t1 = 2 * it + 1;
        KTILE(0, STAGE_A(0, t1, 1),     STAGE_A(1, t1, 1),
                 STAGE_B(0, t1 + 1, 0), STAGE_B(1, t1 + 1, 0), GATE4);
        KTILE(1, STAGE_A(0, t1 + 1, 0), STAGE_A(1, t1 + 1, 0),
                 STAGE_B(0, t1 + 2, 1), STAGE_B(1, t1 + 2, 1), GATE4);
    }
    KTILE(0, STAGE_A(0, 31, 1), STAGE_A(1, 31, 1), NOPS, NOPS, GATE0);
    KTILE(1, NOPS, NOPS, NOPS, NOPS, GATE0);

    {
        unsigned short* Cz = Cqk + (size_t)z * ((size_t)NB * SEQ * DIMN);
        const int crow0 = m0 + wm * 128 + fq * 4;
        const int ccol0 = n0 + wn * 64 + fr;
        #pragma unroll
        for (int mi = 0; mi < 8; mi++)
            #pragma unroll
            for (int ni = 0; ni < 4; ni++) {
                size_t base = (size_t)(crow0 + mi * 16) * DIMN + (ccol0 + ni * 16);
                #pragma unroll
                for (int r = 0; r < 4; r++)
                    Cz[base + (size_t)r * DIMN] = f2b(acc[mi][ni][r]);
            }
    }
}

// =====================================================================
// 128x256 8-phase V GEMM with transposed epilogue. grid (8,32) = 256 blocks.
// =====================================================================
#define VNT 32   // K-tiles of 64

__global__ __launch_bounds__(512, 2) void gemm128_v(
    const unsigned short* __restrict__ A,
    const unsigned short* __restrict__ Bw,   // Wv (bf16)
    unsigned short* __restrict__ vT)
{
    __shared__ alignas(16) unsigned short sA[2][8192];    // [dbuf][128][64]
    __shared__ alignas(16) unsigned short sB[3][16384];   // [3ring][256][64]

    const int fid = blockIdx.y * 8 + blockIdx.x;
    const int sid = (fid & 7) * 32 + (fid >> 3);
    const int bx = sid & 7, by = sid >> 3;           // by 0..31
    const int n0 = bx << 8, m0 = by << 7;

    const int tid  = threadIdx.x;
    const int lane = tid & 63, wave = tid >> 6;
    const int wm = wave >> 2, wn = wave & 3;         // 2M x 4N, per-wave 64x64
    const int fr = lane & 15, fq = lane >> 4;

    const int srow = tid >> 3, sslot = tid & 7;
    const unsigned short* gA_base = A  + (size_t)(m0 + srow) * DIMN + ((sslot ^ (srow & 7)) << 3);
    const unsigned short* gB_base = Bw + (size_t)(n0 + srow) * DIMN + ((sslot ^ (srow & 7)) << 3);

    const int arow = wm * 64 + fr;
    const int brow = wn * 64 + fr;

    f32x4 acc[4][4];
    #pragma unroll
    for (int i = 0; i < 4; i++)
        #pragma unroll
        for (int j = 0; j < 4; j++)
            acc[i][j] = (f32x4){0.f, 0.f, 0.f, 0.f};

#define VSA(t, pa) do { \
    const unsigned short* g_ = gA_base + (size_t)(t) * 64; \
    unsigned short* l_ = &sA[pa][0] + tid * 8; \
    gload_lds16(g_, l_); \
    gload_lds16(g_ + (size_t)(64 * DIMN), l_ + 4096); \
} while (0)
#define VSB_H(h, t, tb) do { \
    const unsigned short* g_ = gB_base + (size_t)((h) * 128) * DIMN + (size_t)(t) * 64; \
    unsigned short* l_ = &sB[tb][(h) * 8192] + tid * 8; \
    gload_lds16(g_, l_); \
    gload_lds16(g_ + (size_t)(64 * DIMN), l_ + 4096); \
} while (0)

#define VLOAD_AF(pa) do { \
    _Pragma("unroll") \
    for (int mi_ = 0; mi_ < 4; mi_++) { \
        const int ra_ = arow + mi_ * 16; \
        _Pragma("unroll") \
        for (int kc_ = 0; kc_ < 2; kc_++) \
            af[mi_][kc_] = *(const bf16x8_a*)&sA[pa][(ra_ << 6) + (((kc_ * 4 + fq) ^ (ra_ & 7)) << 3)]; \
    } \
} while (0)
#define VLOAD_BF(dst, tb, rofs) do { \
    _Pragma("unroll") \
    for (int ni_ = 0; ni_ < 2; ni_++) { \
        const int rb_ = brow + (rofs) + ni_ * 16; \
        _Pragma("unroll") \
        for (int kc_ = 0; kc_ < 2; kc_++) \
            dst[ni_][kc_] = *(const bf16x8_a*)&sB[tb][(rb_ << 6) + (((kc_ * 4 + fq) ^ (rb_ & 7)) << 3)]; \
    } \
} while (0)

#define VMFMA(AF, BF, NBASE) do { \
    _Pragma("unroll") \
    for (int mi_ = 0; mi_ < 4; mi_++) \
    _Pragma("unroll") \
    for (int ni_ = 0; ni_ < 2; ni_++) \
    _Pragma("unroll") \
    for (int kc_ = 0; kc_ < 2; kc_++) \
        acc[mi_][(NBASE) + ni_] = __builtin_amdgcn_mfma_f32_16x16x32_bf16( \
            AF[mi_][kc_], BF[ni_][kc_], acc[mi_][(NBASE) + ni_], 0, 0, 0); \
} while (0)

#define VKT(PA, TB, T2, SA_, SB0_, SB1_, GATE) do { \
    VLOAD_AF(PA); \
    VLOAD_BF(bfA, TB, 0); \
    SA_; SB0_; \
    asm volatile("s_waitcnt lgkmcnt(8)"); \
    __builtin_amdgcn_s_barrier(); \
    asm volatile("s_waitcnt lgkmcnt(0)"); \
    __builtin_amdgcn_s_setprio(1); \
    VMFMA(af, bfA, 0); \
    __builtin_amdgcn_s_setprio(0); \
    __builtin_amdgcn_s_barrier(); \
    VLOAD_BF(bfB, TB, 32); \
    SB1_; \
    __builtin_amdgcn_s_barrier(); \
    asm volatile("s_waitcnt lgkmcnt(0)"); \
    __builtin_amdgcn_s_setprio(1); \
    VMFMA(af, bfB, 2); \
    __builtin_amdgcn_s_setprio(0); \
    GATE; \
    __builtin_amdgcn_s_barrier(); \
} while (0)

    VSA(0, 0);
    VSB_H(0, 0, 0); VSB_H(1, 0, 0);
    VSB_H(0, 1, 1); VSB_H(1, 1, 1);
    asm volatile("s_waitcnt vmcnt(4)");
    __builtin_amdgcn_s_barrier();

    bf16x8 af[4][2], bfA[2][2], bfB[2][2];

    for (int t = 0; t < VNT - 2; ++t) {
        const int PA = t & 1, TB = t % 3, T2 = (t + 2) % 3;
        VKT(PA, TB, T2,
            VSA(t + 1, PA ^ 1),
            VSB_H(0, t + 2, T2),
            VSB_H(1, t + 2, T2),
            GATE4);
    }
    VKT(0, (VNT - 2) % 3, 0, VSA(VNT - 1, 1), NOPS, NOPS, GATE0);
    VKT(1, (VNT - 1) % 3, 0, NOPS, NOPS, NOPS, NOPS);

    // ---- transposed epilogue: row = s (within batch), col = e ----
    {
        const int grow0 = m0 + wm * 64 + fq * 4;
        const int ccol0 = n0 + wn * 64 + fr;
        #pragma unroll
        for (int mi = 0; mi < 4; mi++) {
            const int grow = grow0 + mi * 16;
            const int bb = grow >> 11;            // row -> batch (SEQ=2048)
            const int ss = grow & (SEQ - 1);
            unsigned short* Vb = vT + (size_t)bb * SEQ * DIMN;
            #pragma unroll
            for (int ni = 0; ni < 4; ni++) {
                const int col = ccol0 + ni * 16;
                ushort4 w;
                w.x = f2b(acc[mi][ni][0]);
                w.y = f2b(acc[mi][ni][1]);
                w.z = f2b(acc[mi][ni][2]);
                w.w = f2b(acc[mi][ni][3]);
                *(ushort4_a*)(Vb + (size_t)col * SEQ + ss) = w;
            }
        }
    }
}

// =====================================================================
// 128x256 8-phase OUT-PROJECTION GEMM. grid (8,16,2) = 256 blocks.
// =====================================================================
__global__ __launch_bounds__(512, 2) void gemm128_o(
    const unsigned short* __restrict__ Act,
    const unsigned short* __restrict__ Bw,    // Wo (bf16)
    void* __restrict__ Cout,
    const void* __restrict__ dtp)
{
    __shared__ alignas(16) unsigned short sA[2][8192];    // [dbuf][128][64]
    __shared__ alignas(16) unsigned short sB[3][16384];   // [3ring][256][64]

    const bool cf32 = dt_is_f32(dtp);
    const long long SD = (long long)SEQ * DIMN;

    const int fid = (blockIdx.z * 16 + blockIdx.y) * 8 + blockIdx.x;
    const int sid = (fid & 7) * 32 + (fid >> 3);
    const int bx = sid & 7, rest = sid >> 3;
    const int by = rest & 15, z = rest >> 4;
    const int n0 = bx << 8, m0 = by << 7;

    const int tid  = threadIdx.x;
    const int lane = tid & 63, wave = tid >> 6;
    const int wm = wave >> 2, wn = wave & 3;         // 2M x 4N, per-wave 64x64
    const int fr = lane & 15, fq = lane >> 4;

    const int srow = tid >> 3, sslot = tid & 7;
    const unsigned short* gA_base = Act + (size_t)z * SD + (size_t)(m0 + srow) * DIMN + ((sslot ^ (srow & 7)) << 3);
    const unsigned short* gB_base = Bw + (size_t)(n0 + srow) * DIMN + ((sslot ^ (srow & 7)) << 3);

    const int arow = wm * 64 + fr;
    const int brow = wn * 64 + fr;

    f32x4 acc[4][4];
    #pragma unroll
    for (int i = 0; i < 4; i++)
        #pragma unroll
        for (int j = 0; j < 4; j++)
            acc[i][j] = (f32x4){0.f, 0.f, 0.f, 0.f};

    VSA(0, 0);
    VSB_H(0, 0, 0); VSB_H(1, 0, 0);
    VSB_H(0, 1, 1); VSB_H(1, 1, 1);
    asm volatile("s_waitcnt vmcnt(4)");
    __builtin_amdgcn_s_barrier();

    bf16x8 af[4][2], bfA[2][2], bfB[2][2];

    for (int t = 0; t < VNT - 2; ++t) {
        const int PA = t & 1, TB = t % 3, T2 = (t + 2) % 3;
        VKT(PA, TB, T2,
            VSA(t + 1, PA ^ 1),
            VSB_H(0, t + 2, T2),
            VSB_H(1, t + 2, T2),
            GATE4);
    }
    VKT(0, (VNT - 2) % 3, 0, VSA(VNT - 1, 1), NOPS, NOPS, GATE0);
    VKT(1, (VNT - 1) % 3, 0, NOPS, NOPS, NOPS, NOPS);

    {
        const int crow0 = m0 + wm * 64 + fq * 4;
        const int ccol0 = n0 + wn * 64 + fr;
        #pragma unroll
        for (int mi = 0; mi < 4; mi++)
            #pragma unroll
            for (int ni = 0; ni < 4; ni++) {
                size_t base = (size_t)(crow0 + mi * 16) * DIMN + (ccol0 + ni * 16);
                if (cf32) {
                    float* Cz = (float*)Cout + (size_t)z * SD;
                    #pragma unroll
                    for (int r = 0; r < 4; r++)
                        Cz[base + (size_t)r * DIMN] = acc[mi][ni][r];
                } else {
                    unsigned short* Cz = (unsigned short*)Cout + (size_t)z * SD;
                    #pragma unroll
                    for (int r = 0; r < 4; r++)
                        Cz[base + (size_t)r * DIMN] = f2b(acc[mi][ni][r]);
                }
            }
    }
}

// =====================================================================
extern "C" void kernel_launch(void* const* d_in, const int* in_sizes, int n_in,
                              void* d_out, int out_size, void* d_ws, size_t ws_size,
                              hipStream_t stream)
{
    const void* x  = d_in[0];
    const void* Wq = d_in[1];
    const void* Wk = d_in[2];
    const void* Wv = d_in[3];
    const void* Wo = d_in[4];
    const void* fc = d_in[5];
    const void* fs = d_in[6];

    const size_t NX = (size_t)NB * SEQ * DIMN;   // 8.39M elems
    const size_t NW = (size_t)DIMN * DIMN;       // 4.19M elems
    unsigned short* wsp = (unsigned short*)d_ws;
    dim3 blk(256);
    const long long SD = (long long)SEQ * DIMN;
    dim3 gcx((int)(NX / 8 / 256));               // convert grid for x-sized bufs
    dim3 gcw((int)(NW / 8 / 256));               // convert grid for W-sized bufs
    dim3 gr((int)(NX / 8 / 256), 2, 1);          // rope (non-fused path)
    dim3 gt(SEQ / 32, DIMN / 32, NB);            // transpose (non-fused path)
    dim3 gf(NQT * NBH, 1, 1);                    // flash (1D, pair-balanced qt)
    dim3 gp(DIMN / 128, DIMN / 128, NB);         // out gemm (non-fused path)

    const bool fused = ws_size >= (NX + 3 * NW + 3 * NX) * sizeof(unsigned short);

    if (fused) {
        // layout: xb | wqkv(3W) | q,k,vT.  ctxT<-wqkv, wob<-wqkv+NX (=Wv slot,
        // free after gemm128_v consumes Wv)
        unsigned short* xb    = wsp;
        unsigned short* wqkv  = xb + NX;
        unsigned short* q_lin = wqkv + 3 * NW;
        unsigned short* k_lin = q_lin + NX;
        unsigned short* vT2   = k_lin + NX;      // V written transposed directly
        unsigned short* ctxT  = wqkv;
        unsigned short* wob   = wqkv + NX;

        dim3 gc4((NX8 + 3 * NW8) / 256);
        convert4_kernel<<<gc4, blk, 0, stream>>>(x, Wq, Wk, Wv, xb, wqkv, fc);

        dim3 g256(8, 16, 2);                     // Q,K: 256 blocks = 1 full round
        gemm256_qkv<<<g256, dim3(512), 0, stream>>>(xb, wqkv, q_lin);
        dim3 gv(8, 32, 1);                       // V: 256 blocks = 1 half round
        gemm128_v<<<gv, dim3(512), 0, stream>>>(xb, wqkv + 2 * NW, vT2);

        dim3 gr3((int)(NX / 8 / 256), 3, 1);     // rope q,k + convert Wo in one launch
        rope_convwo_kernel<<<gr3, blk, 0, stream>>>(q_lin, k_lin, Wo, wob, fc, fs);

        flash_kernel<<<gf, blk, 0, stream>>>(q_lin, k_lin, vT2, ctxT);

        dim3 go(8, 16, 2);                       // out-proj: 256 blocks = 1 round
        gemm128_o<<<go, dim3(512), 0, stream>>>(ctxT, wob, d_out, fc);
    } else {
        // layout: xb | wb | q | k | v.  vT<-xb, ctxT<-v_lin, wob<-wb   (75.5 MB)
        unsigned short* xb    = wsp;
        unsigned short* wb    = xb + NX;
        unsigned short* q_lin = wb + NW;
        unsigned short* k_lin = q_lin + NX;
        unsigned short* v_lin = k_lin + NX;
        unsigned short* vT    = xb;
        unsigned short* ctxT  = v_lin;

        convert_kernel<<<gcx, blk, 0, stream>>>(x, xb, (int)(NX / 8), fc);
        dim3 g1(DIMN / 128, (NB * SEQ) / 128, 1);
        convert_kernel<<<gcw, blk, 0, stream>>>(Wq, wb, (int)(NW / 8), fc);
        gemm_bt<<<g1, blk, 0, stream>>>(xb, wb, q_lin, fc, 0,
            DIMN, DIMN, DIMN, DIMN, 1, 0, 0, 0, 0, 0, 0, 1.0f);
        convert_kernel<<<gcw, blk, 0, stream>>>(Wk, wb, (int)(NW / 8), fc);
        gemm_bt<<<g1, blk, 0, stream>>>(xb, wb, k_lin, fc, 0,
            DIMN, DIMN, DIMN, DIMN, 1, 0, 0, 0, 0, 0, 0, 1.0f);
        convert_kernel<<<gcw, blk, 0, stream>>>(Wv, wb, (int)(NW / 8), fc);
        gemm_bt<<<g1, blk, 0, stream>>>(xb, wb, v_lin, fc, 0,
            DIMN, DIMN, DIMN, DIMN, 1, 0, 0, 0, 0, 0, 0, 1.0f);

        rope_kernel<<<gr, blk, 0, stream>>>(q_lin, k_lin, fc, fs);
        transpose_kernel<<<gt, blk, 0, stream>>>(v_lin, vT);
        flash_kernel<<<gf, blk, 0, stream>>>(q_lin, k_lin, vT, ctxT);

        convert_kernel<<<gcw, blk, 0, stream>>>(Wo, wb, (int)(NW / 8), fc);
        gemm_bt<<<gp, blk, 0, stream>>>(ctxT, wb, d_out, fc, 1,
            SEQ, SEQ, DIMN, DIMN, 1, SD, 0, 0, 0, SD, 0, 1.0f);
    }
}